// Round 1
// baseline (1772.589 us; speedup 1.0000x reference)
//
#include <hip/hip_runtime.h>
#include <hip/hip_bf16.h>
#include <stdint.h>

typedef __hip_bfloat16 bf16_t;
typedef __attribute__((ext_vector_type(4))) float f32x4;
typedef __attribute__((ext_vector_type(8))) short s16x8;

#define UNITS 768
#define NCOLS 3072        // 4*UNITS (gates, reordered)
#define NPRED 96
#define NPAD  3200        // 25 tiles of 128
#define MROWS 2048
#define BM 128
#define BN 128
#define BK 32

// async global->LDS, 16B per lane, LDS dest = wave-uniform base + lane*16
#define GLL16(ldsp, gp) \
  __builtin_amdgcn_global_load_lds((const __attribute__((address_space(1))) void*)(gp), \
                                   (__attribute__((address_space(3))) void*)(ldsp), 16, 0, 0)

__device__ __forceinline__ float sigf(float x) {
    return __builtin_amdgcn_rcpf(1.f + __expf(-x));
}
__device__ __forceinline__ float tanh_fast(float x) {
    return 1.f - 2.f * __builtin_amdgcn_rcpf(1.f + __expf(2.f * x));
}

// ---------------- prep kernels (run once per launch, off critical path) ---------------

// B0T[c][k] = W_ih[g*768+u][k], c-reordered, K=96, c in [0,3072)
__global__ void prep_b0(const float* __restrict__ W_ih, bf16_t* __restrict__ B0T) {
    int idx = blockIdx.x * 256 + threadIdx.x;
    if (idx >= NCOLS * 96) return;
    int c = idx / 96, k = idx % 96;
    int u = ((c >> 6) << 4) + (c & 15);
    int g = (c >> 4) & 3;
    B0T[idx] = (bf16_t)W_ih[(g * UNITS + u) * 96 + k];
}

// x0[b][k] = inputs[b][23][k]  (bf16)
__global__ void prep_x0(const float* __restrict__ inputs, bf16_t* __restrict__ x0) {
    int idx = blockIdx.x * 256 + threadIdx.x; // < 2048*96 exactly
    int b = idx / 96, k = idx % 96;
    x0[idx] = (bf16_t)inputs[(b * 24 + 23) * 96 + k];
}

// b0_r[c] = b_ih+b_hh (reordered); beff_r[c] = b0_r + (W_ih @ b_d)
__global__ void prep_bias(const float* __restrict__ b_ih, const float* __restrict__ b_hh,
                          const float* __restrict__ W_ih, const float* __restrict__ b_d,
                          float* __restrict__ b0_r, float* __restrict__ beff_r) {
    int c = blockIdx.x * 256 + threadIdx.x;
    if (c >= NCOLS) return;
    int u = ((c >> 6) << 4) + (c & 15);
    int g = (c >> 4) & 3;
    int r = g * UNITS + u;
    float v = b_ih[r] + b_hh[r];
    float acc = 0.f;
    for (int j = 0; j < 96; ++j) acc += W_ih[r * 96 + j] * b_d[j];
    b0_r[c] = v;
    beff_r[c] = v + acc;
}

// BeffT[c][k]: c<3072: W_hh + W_ih@W_d (reordered cols); 3072..3167: W_d rows; pad zero. K=768
__global__ void prep_beff(const float* __restrict__ W_hh, const float* __restrict__ W_ih,
                          const float* __restrict__ W_d, bf16_t* __restrict__ BeffT) {
    int idx = blockIdx.x * 256 + threadIdx.x;
    if (idx >= NPAD * UNITS) return;
    int c = idx / UNITS, k = idx % UNITS;
    if (c < NCOLS) {
        int u = ((c >> 6) << 4) + (c & 15);
        int g = (c >> 4) & 3;
        int r = g * UNITS + u;
        float acc = W_hh[(size_t)r * UNITS + k];
        for (int j = 0; j < 96; ++j) acc += W_ih[r * 96 + j] * W_d[j * UNITS + k];
        BeffT[idx] = (bf16_t)acc;
    } else if (c < NCOLS + NPRED) {
        BeffT[idx] = (bf16_t)W_d[(c - NCOLS) * UNITS + k];
    } else {
        BeffT[idx] = (bf16_t)0.f;
    }
}

// ---------------- main step kernel ---------------
// One GEMM (M=2048, N=tiles*128, K=Kdim) with fused LSTM-cell epilogue on gate tiles
// (nt<24) and pred store on tile 24.  A: M x K row-major bf16.  BT: N x K row-major bf16.
__global__ __launch_bounds__(256, 2)
void step_kernel(const bf16_t* __restrict__ A,
                 const bf16_t* __restrict__ BT,
                 const float* __restrict__ bias_r,
                 const float* __restrict__ b_d,
                 float* __restrict__ c_state,
                 bf16_t* __restrict__ h_out,
                 float* __restrict__ out,
                 int Kdim, int col_tile_base, int t, int is_first)
{
    __shared__ bf16_t sA[BM * BK];   // [row][k], 64B rows, no padding (global_load_lds layout)
    __shared__ bf16_t sB[BN * BK];

    const int tid = threadIdx.x;
    const int wave = tid >> 6;
    const int lane = tid & 63;
    const int wr = wave >> 1, wc = wave & 1;
    const int l15 = lane & 15, l4 = lane >> 4;

    const int mt = blockIdx.x;
    const int nt = col_tile_base + blockIdx.y;
    const int m0 = mt * BM;
    const int n0 = nt * BN;

    f32x4 acc[4][4];
#pragma unroll
    for (int i = 0; i < 4; ++i)
#pragma unroll
        for (int j = 0; j < 4; ++j) acc[i][j] = f32x4{0.f, 0.f, 0.f, 0.f};

    const int o0 = wave * 1024 + lane * 16;   // byte offset within 8KB tile
    const int nk = Kdim >> 5;

    for (int kt = 0; kt < nk; ++kt) {
        const int k0 = kt << 5;
#pragma unroll
        for (int r = 0; r < 2; ++r) {
            int ob = o0 + r * 4096;
            int row = ob >> 6;
            int kb = ob & 63;
            const bf16_t* gA = A + (size_t)(m0 + row) * Kdim + k0 + (kb >> 1);
            GLL16(sA + ((wave * 1024 + r * 4096) >> 1), gA);
            const bf16_t* gB = BT + (size_t)(n0 + row) * Kdim + k0 + (kb >> 1);
            GLL16(sB + ((wave * 1024 + r * 4096) >> 1), gB);
        }
        __syncthreads();

        s16x8 af[4], bfr[4];
        const char* sAc = (const char*)sA;
        const char* sBc = (const char*)sB;
#pragma unroll
        for (int f = 0; f < 4; ++f) {
            af[f]  = *(const s16x8*)(sAc + (wr * 64 + f * 16 + l15) * 64 + l4 * 16);
            bfr[f] = *(const s16x8*)(sBc + (wc * 64 + f * 16 + l15) * 64 + l4 * 16);
        }
#pragma unroll
        for (int i = 0; i < 4; ++i)
#pragma unroll
            for (int j = 0; j < 4; ++j)
                acc[i][j] = __builtin_amdgcn_mfma_f32_16x16x32_bf16(af[i], bfr[j], acc[i][j], 0, 0, 0);
        __syncthreads();
    }

    // ---- epilogue ----
    if (nt < 24) {
        // gate tile: lane's 4 fn-frags are gates i,f,g,o of unit u (column permutation)
        const int u = nt * 32 + wc * 16 + l15;
        float bi[4];
#pragma unroll
        for (int f = 0; f < 4; ++f) bi[f] = bias_r[n0 + wc * 64 + f * 16 + l15];
#pragma unroll
        for (int i = 0; i < 4; ++i) {
#pragma unroll
            for (int r = 0; r < 4; ++r) {
                int row = m0 + wr * 64 + i * 16 + l4 * 4 + r;
                float gi = acc[i][0][r] + bi[0];
                float gf = acc[i][1][r] + bi[1];
                float gg = acc[i][2][r] + bi[2];
                float go = acc[i][3][r] + bi[3];
                float si = sigf(gi);
                float sf = sigf(gf);
                float tg = tanh_fast(gg);
                float so = sigf(go);
                size_t cidx = (size_t)row * UNITS + u;
                float cold = is_first ? 0.f : c_state[cidx];
                float cn = sf * cold + si * tg;
                c_state[cidx] = cn;
                h_out[cidx] = (bf16_t)(so * tanh_fast(cn));
            }
        }
    } else {
        // pred tile: cols 3072..3167 are W_d rows -> out[:, t-1, :]
#pragma unroll
        for (int f = 0; f < 4; ++f) {
            int j = wc * 64 + f * 16 + l15;
            if (j < NPRED) {
                float bd = b_d[j];
#pragma unroll
                for (int i = 0; i < 4; ++i)
#pragma unroll
                    for (int r = 0; r < 4; ++r) {
                        int row = m0 + wr * 64 + i * 16 + l4 * 4 + r;
                        out[((size_t)row * 64 + (t - 1)) * NPRED + j] = acc[i][f][r] + bd;
                    }
            }
        }
    }
}

extern "C" void kernel_launch(void* const* d_in, const int* in_sizes, int n_in,
                              void* d_out, int out_size, void* d_ws, size_t ws_size,
                              hipStream_t stream)
{
    const float* inputs = (const float*)d_in[0];
    const float* W_ih   = (const float*)d_in[1];
    const float* W_hh   = (const float*)d_in[2];
    const float* b_ih   = (const float*)d_in[3];
    const float* b_hh   = (const float*)d_in[4];
    const float* W_d    = (const float*)d_in[5];
    const float* b_d    = (const float*)d_in[6];
    float* out = (float*)d_out;

    char* ws = (char*)d_ws;
    size_t off = 0;
    auto alloc = [&](size_t bytes) -> char* {
        char* p = ws + off;
        off = (off + bytes + 255) & ~(size_t)255;
        return p;
    };
    bf16_t* B0T   = (bf16_t*)alloc((size_t)NCOLS * 96 * 2);
    bf16_t* BeffT = (bf16_t*)alloc((size_t)NPAD * UNITS * 2);
    bf16_t* x0    = (bf16_t*)alloc((size_t)MROWS * 96 * 2);
    bf16_t* h0    = (bf16_t*)alloc((size_t)MROWS * UNITS * 2);
    bf16_t* h1    = (bf16_t*)alloc((size_t)MROWS * UNITS * 2);
    float*  cst   = (float*)alloc((size_t)MROWS * UNITS * 4);
    float*  b0r   = (float*)alloc(NCOLS * 4);
    float*  beffr = (float*)alloc(NCOLS * 4);

    prep_b0  <<<(NCOLS * 96 + 255) / 256, 256, 0, stream>>>(W_ih, B0T);
    prep_x0  <<<(MROWS * 96) / 256, 256, 0, stream>>>(inputs, x0);
    prep_bias<<<(NCOLS + 255) / 256, 256, 0, stream>>>(b_ih, b_hh, W_ih, b_d, b0r, beffr);
    prep_beff<<<((size_t)NPAD * UNITS + 255) / 256, 256, 0, stream>>>(W_hh, W_ih, W_d, BeffT);

    bf16_t* h[2] = {h0, h1};

    // iter 0: gates from x0 (K=96), h=c=0, no pred tile
    step_kernel<<<dim3(16, 24), 256, 0, stream>>>(x0, B0T, b0r, b_d, cst, h[1], out,
                                                  96, 0, 0, 1);
    // iters 1..63: gates_n = h_n @ W_eff^T (K=768) + pred_{n-1} columns
    for (int n = 1; n < 64; ++n)
        step_kernel<<<dim3(16, 25), 256, 0, stream>>>(h[n & 1], BeffT, beffr, b_d, cst,
                                                      h[(n + 1) & 1], out, UNITS, 0, n, 0);
    // tail: pred_63 = h_64 @ W_d^T + b_d  (pred tile only)
    step_kernel<<<dim3(16, 1), 256, 0, stream>>>(h[0], BeffT, beffr, b_d, cst, h[1], out,
                                                 UNITS, 24, 64, 0);
}